// Round 2
// baseline (235.159 us; speedup 1.0000x reference)
//
#include <hip/hip_runtime.h>
#include <math.h>

// Match numpy's separate mul/add roundings — no implicit FMA contraction.
// (Explicit __builtin_fmaf below is intentional and unaffected.)
#pragma clang fp contract(off)

#define TPB 256
#define ROWLEN 1024
#define PERSIST_BLOCKS 2048   // 8 blocks/CU * 256 CU; 32768 rows -> 16 rows/block

// Native clang vector type (required by __builtin_nontemporal_store).
typedef float f32x4 __attribute__((ext_vector_type(4)));

// ---- DPP wave64 reductions (VALU-only; ~4cyc/stage, no LDS pipe) ----
__device__ __forceinline__ float wave_max_dpp(float m) {
    const int NEG_INF = 0xff800000;             // -inf bits (fmax identity)
    int v;
    v = __builtin_amdgcn_update_dpp(NEG_INF, __float_as_int(m), 0x111, 0xf, 0xf, false);
    m = fmaxf(m, __int_as_float(v));
    v = __builtin_amdgcn_update_dpp(NEG_INF, __float_as_int(m), 0x112, 0xf, 0xf, false);
    m = fmaxf(m, __int_as_float(v));
    v = __builtin_amdgcn_update_dpp(NEG_INF, __float_as_int(m), 0x114, 0xf, 0xf, false);
    m = fmaxf(m, __int_as_float(v));
    v = __builtin_amdgcn_update_dpp(NEG_INF, __float_as_int(m), 0x118, 0xf, 0xf, false);
    m = fmaxf(m, __int_as_float(v));
    v = __builtin_amdgcn_update_dpp(NEG_INF, __float_as_int(m), 0x142, 0xa, 0xf, false);
    m = fmaxf(m, __int_as_float(v));
    v = __builtin_amdgcn_update_dpp(NEG_INF, __float_as_int(m), 0x143, 0xc, 0xf, false);
    m = fmaxf(m, __int_as_float(v));
    return __int_as_float(__builtin_amdgcn_readlane(__float_as_int(m), 63));
}

__device__ __forceinline__ unsigned wave_sum_dpp_u32(unsigned a) {
    int v;
    v = __builtin_amdgcn_update_dpp(0, (int)a, 0x111, 0xf, 0xf, false); a += (unsigned)v;
    v = __builtin_amdgcn_update_dpp(0, (int)a, 0x112, 0xf, 0xf, false); a += (unsigned)v;
    v = __builtin_amdgcn_update_dpp(0, (int)a, 0x114, 0xf, 0xf, false); a += (unsigned)v;
    v = __builtin_amdgcn_update_dpp(0, (int)a, 0x118, 0xf, 0xf, false); a += (unsigned)v;
    v = __builtin_amdgcn_update_dpp(0, (int)a, 0x142, 0xa, 0xf, false); a += (unsigned)v;
    v = __builtin_amdgcn_update_dpp(0, (int)a, 0x143, 0xc, 0xf, false); a += (unsigned)v;
    return (unsigned)__builtin_amdgcn_readlane((int)a, 63);
}

// BLOCK-per-row, PERSISTENT grid with cross-row prefetch.
//
// The one-shot block-per-row version launched 32768 blocks; each block's
// critical path starts with a cold ~900cy HBM load that nothing hides
// (prior session: no pipe >35% busy => latency wall). This version keeps
// 2048 resident blocks (8/CU) alive over 16 rows each and issues row
// r+stride's dwordx4 load BEFORE computing row r — the HBM latency then
// overlaps the reduce/exp/epilogue chain (~2000cy), and the ~30-op
// double-float preamble runs once per block instead of once per row.
//
// Numerics: identical per-row math to the verified 224us kernel
// (absmax 4.27e-4 family):
//  - 1/sf, b, c, x0 via double-float Newton (rh+rl ~ 2^-46 rel).
//  - x/sf: double-float multiply + exact-residual FMA ~= CR f32 division.
//  - exp_int: pure f32 mul/add/ldexp/floor — bit-identical to numpy.
//  - Row sum: per-lane u32 exact; lo16/hi16 DPP chains exact; cross-wave
//    exact-integer doubles in LDS; factor = floor(2^32/sum) exact.
//  - Epilogue reciprocals f32-rounded: rare +-1 A-quantum flips,
//    3.9e-4 << 1.87e-3 threshold.
//
// LDS reuse across iterations is barrier-safe: smax(i) reads happen
// before the sum-barrier of iter i, and smax(i+1) writes after it;
// ssum(i) reads happen before the max-barrier of iter i+1, and ssum(i+1)
// writes after it. The loop exit is block-uniform (r identical across
// the block), so __syncthreads pairing is uniform.
__global__ __launch_bounds__(TPB) void qsplit_int_softmax_kernel(
    const float* __restrict__ x,
    const float* __restrict__ scale_p,
    const float* __restrict__ thr_p,
    float* __restrict__ out,
    const int rows)
{
    const int tid  = threadIdx.x;
    const int lane = tid & 63;
    const int wid  = tid >> 6;

    __shared__ float  smax[4];
    __shared__ double ssum[4];

    const float sf  = scale_p[0];   // 0.05f
    const float thr = thr_p[0];     // 0.1f

    // ---- lean f32 preamble: double-float 1/sf (once per BLOCK) ----
    const float rh = 1.0f / sf;                            // IEEE f32 div
    const float er = __builtin_fmaf(-sf, rh, 1.0f);        // residual
    const float rl = rh * er;                              // rh+rl ~ 1/sf @2^-46

    // q = a/sf in double-float, then floor (margins: .137/.147/.845)
    #define DF_DIV(a) ({ float _p = (a) * rh; \
                         float _e = __builtin_fmaf((a), rh, -_p); \
                         _p + __builtin_fmaf((a), rl, _e); })
    const float x0f    = floorf(DF_DIV(-0.69314718f));           // -14
    const float bfc    = floorf(DF_DIV(2.7073824f));             // 54  (c1/c0)
    const float s2     = sf * sf;
    const float r2h    = 1.0f / s2;
    const float r2e    = __builtin_fmaf(-s2, r2h, 1.0f);
    const float r2l    = r2h * r2e;
    const float cq     = __builtin_fmaf(2.7921141f, r2l,
                         2.7921141f * r2h);                      // c2/c0/sf^2
    const float cfc    = floorf(cq);                             // 1116
    const float clampf = 15.0f * x0f;                            // -210 exact
    const float invx0f = 1.0f / x0f;

    const float osA  = thr / 255.0f;         // f32 div, as numpy
    const float osB  = 1.0f / 255.0f;
    const float invA = 1.0f / (4294967296.0f * osA);   // <=1ulp vs CR div
    const float invB = 1.0f / (4294967296.0f * osB);
    const float thrq = floorf(thr * 256.0f);           // 25

    const int stride = gridDim.x;
    int r = blockIdx.x;
    if (r >= rows) return;

    // ---- prime the pipeline: load row r (one dwordx4/thread) ----
    f32x4 xv = *(const f32x4*)(x + (size_t)r * ROWLEN + (size_t)tid * 4);

    for (;;) {
        // ---- issue NEXT row's load first: HBM latency hides under this
        //      row's reduce/exp/epilogue work ----
        const int rn = r + stride;
        const bool has_next = (rn < rows);   // block-uniform branch
        f32x4 xn;
        if (has_next)
            xn = *(const f32x4*)(x + (size_t)rn * ROWLEN + (size_t)tid * 4);

        // ---- x_int = x/sf via double-float (~CR f32 division) ----
        float xi[4];
        #pragma unroll
        for (int j = 0; j < 4; ++j) {
            const float xx = xv[j];
            const float p  = xx * rh;
            const float e  = __builtin_fmaf(xx, rh, -p);   // exact residual
            xi[j] = p + __builtin_fmaf(xx, rl, e);
        }

        // ---- row max: local + DPP + tiny LDS cross-wave ----
        float m = fmaxf(fmaxf(xi[0], xi[1]), fmaxf(xi[2], xi[3]));
        m = wave_max_dpp(m);
        if (lane == 0) smax[wid] = m;
        __syncthreads();
        m = fmaxf(fmaxf(smax[0], smax[1]), fmaxf(smax[2], smax[3]));

        // ---- integer exp (f32/int, bit-matching numpy) ----
        float e4[4];
        unsigned usum = 0;    // <= 4 * 3.66e7 < 2^28: exact
        #pragma unroll
        for (int j = 0; j < 4; ++j) {
            float v = xi[j] - m;                  // exact f32 sub
            v = fmaxf(v, clampf);                 // >= -210
            const float qf = floorf(v * invx0f);  // in [0,15]; flips benign
            const int   qi = (int)qf;
            const float rr = v - x0f * qf;        // exact in f32
            const float t  = rr + bfc;
            const float z  = rr * t + cfc;        // two roundings (contract off)
            float ei = floorf(ldexpf(z, 15 - qi)); // pow2 scale exact
            ei = fmaxf(ei, 0.0f);
            e4[j] = ei;
            usum += (unsigned)ei;
        }

        // ---- row sum: lo/hi u32 DPP (exact) + exact-int doubles in LDS ----
        const unsigned lo = wave_sum_dpp_u32(usum & 0xFFFFu);  // < 2^22
        const unsigned hi = wave_sum_dpp_u32(usum >> 16);      // < 2^20
        if (lane == 0)
            ssum[wid] = (double)(((unsigned long long)hi << 16) + lo); // exact int
        __syncthreads();
        const double s = ((ssum[0] + ssum[1]) + ssum[2]) + ssum[3];    // exact

        // ---- row-uniform epilogue constants (f64: ~3 ops per row) ----
        const float fac_f = (float)floor(4294967296.0 / s);   // int < 2^17: exact
        const float ath_f = (float)(((double)thrq * s) * (1.0 / 256.0));

        // ---- quantize + nontemporal store ----
        f32x4 o;
        #pragma unroll
        for (int j = 0; j < 4; ++j) {
            const float ei  = e4[j];
            const bool  isA = (ei <= ath_f);
            const float t1  = ei * fac_f;               // bit-matches numpy
            const float t2  = t1 * (isA ? invA : invB); // ~f32 division
            float si = floorf(t2);
            si = fminf(si, isA ? 3.0e38f : 255.0f);     // cap only B path
            o[j] = si * (isA ? osA : osB);
        }
        __builtin_nontemporal_store(o, (f32x4*)(out + (size_t)r * ROWLEN + (size_t)tid * 4));

        if (!has_next) break;
        r  = rn;
        xv = xn;
    }
}

extern "C" void kernel_launch(void* const* d_in, const int* in_sizes, int n_in,
                              void* d_out, int out_size, void* d_ws, size_t ws_size,
                              hipStream_t stream) {
    const float* x     = (const float*)d_in[0];
    const float* scale = (const float*)d_in[1];
    const float* thr   = (const float*)d_in[2];
    float* out = (float*)d_out;

    const int total = in_sizes[0];        // 2*16*1024*1024
    const int rows  = total / ROWLEN;     // 32768 rows

    const int blocks = rows < PERSIST_BLOCKS ? rows : PERSIST_BLOCKS;

    qsplit_int_softmax_kernel<<<dim3(blocks), dim3(TPB), 0, stream>>>(
        x, scale, thr, out, rows);
}